// Round 6
// baseline (162.688 us; speedup 1.0000x reference)
//
#include <hip/hip_runtime.h>

typedef unsigned int u32;
typedef unsigned short u16;
typedef unsigned char u8;
typedef unsigned long long u64;

typedef __attribute__((ext_vector_type(8))) short bf16x8;
typedef __attribute__((ext_vector_type(4))) float f32x4;
typedef __attribute__((ext_vector_type(4))) u32 u32x4;

#define L_SEQ 200
#define ST_ROWS 208   // 13 tiles * 16 rows (max for L=200)
#define RND9 9        // ceil(208 / 24)  (24 rows/round: 8 lanes x 32B per row)

// R21: R20 fusion with the staging-queue aliasing FIXED. R20's bug: 3 slots,
// consume at j-DEPTH with DEPTH=3 -> (j-3)%3 == j%3, consume read the slot
// the same iteration's load had just overwritten (rounds 0..2 got rounds
// 3..5's rows). Fix: consume at j-2 (R17-proven: slots differ mod 3).
// Fusion rationale (unchanged): bench total = kernel + ~88us constant across
// R15..R19; prep re-converted the 12.8MB table EVERY dispatch + full
// inter-kernel drain. Fused: per-wave len scan (no barrier), per-wave B-frag
// build from L2-hot tranW, direct f32 emb gather -> pk2bf -> swizzled
// ds_write_b128. ONE launch, no ws.
// Kept verified pieces: XOR-swizzled LDS layout + tile loop (R17/R19), DPP
// row16 reduce, ids-before-gathers (R16), masked rows -> zero row (R18),
// balanced epilogue (R19). absmax target 3.05e-5.
__device__ __forceinline__ u16 f2bf(float f) {
    u32 u = __float_as_uint(f);
    return (u16)((u + 0x7FFFu + ((u >> 16) & 1u)) >> 16);  // RNE
}
__device__ __forceinline__ u32 pk2bf(float fx, float fy) {  // round-half-up pair pack
    u32 xb = __float_as_uint(fx) + 0x8000u;
    u32 yb = __float_as_uint(fy) + 0x8000u;
    return __byte_perm(xb, yb, 0x7632);
}

// sum over the 16-lane DPP row (lanes 16g..16g+15); every lane gets the total.
// row_ror:k = 0x120|k. Pure VALU: no LDS-pipe latency in the per-tile chain.
__device__ __forceinline__ float row16_sum(float v) {
    int x;
    x = __builtin_amdgcn_update_dpp(0, __float_as_int(v), 0x128, 0xF, 0xF, true);
    v += __int_as_float(x);
    x = __builtin_amdgcn_update_dpp(0, __float_as_int(v), 0x124, 0xF, 0xF, true);
    v += __int_as_float(x);
    x = __builtin_amdgcn_update_dpp(0, __float_as_int(v), 0x122, 0xF, 0xF, true);
    v += __int_as_float(x);
    x = __builtin_amdgcn_update_dpp(0, __float_as_int(v), 0x121, 0xF, 0xF, true);
    v += __int_as_float(x);
    return v;
}
__device__ __forceinline__ float wave_sumf(float v) {
    v = row16_sum(v);
    v += __shfl_xor(v, 16, 64);
    v += __shfl_xor(v, 32, 64);
    return v;
}

// ---- single fused kernel: block = 1 sample = 3 waves; wave = attr ----------
__global__ __launch_bounds__(192, 4) void etna_fused(
    const int* __restrict__ x, const void* __restrict__ xmask,
    const float* __restrict__ ob, const float* __restrict__ emb,
    const float* __restrict__ tranW, const float* __restrict__ tranb,
    const float* __restrict__ attW, const float* __restrict__ attb,
    const float* __restrict__ W0, const float* __restrict__ W1,
    const float* __restrict__ W2, float* __restrict__ out, int Vn) {
    __shared__ __align__(16) float ldsf[ST_ROWS * 32];  // staged rows, swizzled
    __shared__ float rep[3][64];                        // post-tanh user rep
    char* ldsb = (char*)ldsf;

    const int tid = threadIdx.x;
    const int a = tid >> 6;     // wave = attribute
    const int lane = tid & 63;
    const int col = lane & 15;  // A row m / B+D col n
    const int g = lane >> 4;    // k-chunk / D row group
    const int b = blockIdx.x;

    // ---- x_mask encoding detection (first 800 bytes; per-wave, L2-hot) ----
    int esz;
    {
        u32 accF = 0, acc0 = 0, accO = 0;
#pragma unroll
        for (int k = 0; k < 4; ++k) {
            int i = lane + 64 * k;
            u32 w = (i < 200) ? ((const u32*)xmask)[i] : 0u;
            accF |= (w & 0xFEFEFEFEu);
            acc0 |= (w & 0x000000FFu);
            accO |= (w & 0xFFFFFF00u);
        }
        bool isFloat = __ballot(accF != 0) != 0;
        bool hasB0   = __ballot(acc0 != 0) != 0;
        bool hasOdd  = __ballot(accO != 0) != 0;
        esz = isFloat ? (hasB0 ? 2 : 4) : (hasOdd ? 1 : 4);
    }

    // ---- len: each wave scans its own sample (identical result, no barrier)
    int len = 0;
    {
        int mbase = b * L_SEQ;
#pragma unroll
        for (int c4 = 0; c4 < 4; ++c4) {
            int l = c4 * 64 + lane;
            bool v = false;
            if (l < L_SEQ) {
                int off = mbase + l;
                if (esz == 1)      v = ((const u8*)xmask)[off] != 0;
                else if (esz == 2) v = ((const u16*)xmask)[off] != 0;
                else               v = ((const u32*)xmask)[off] != 0;
            }
            len += (int)__popcll(__ballot(v));
        }
    }

    // ---- B-frags built directly from tranW (L2-hot 48KB; 64 loads/lane) ----
    // elem jj of frag (c,kh) = tranW[a][kh*32+g*8+jj][c*16+col]  (prep-verified
    // indexing); pairs packed RNE to match the old frag image bit-exactly.
    bf16x8 Bf[4][2];
#pragma unroll
    for (int c = 0; c < 4; ++c)
#pragma unroll
        for (int kh = 0; kh < 2; ++kh) {
            const float* tp = tranW + a * 4096 + (kh * 32 + g * 8) * 64 + c * 16 + col;
            u32x4 wv_;
#pragma unroll
            for (int m = 0; m < 4; ++m) {
                float f0 = tp[(2 * m) * 64];
                float f1 = tp[(2 * m + 1) * 64];
                wv_[m] = (u32)f2bf(f0) | ((u32)f2bf(f1) << 16);
            }
            Bf[c][kh] = __builtin_bit_cast(bf16x8, wv_);
        }

    // per-lane constants (C-layout dim = c*16+col); LOG2E folded into AW/AB
    const float LOG2E = 1.44269504088896f;
    float TB[4], AW[4];
#pragma unroll
    for (int c = 0; c < 4; ++c) {
        TB[c] = tranb[a * 64 + c * 16 + col];
        AW[c] = attW[a * 64 + c * 16 + col] * LOG2E;
    }
    const float AB = attb[a] * LOG2E;

    const int* xrow = x + b * L_SEQ;
    const int nt = (len + 15) >> 4;         // tiles
    const int stRows = nt << 4;             // rows to stage
    const int rounds = (stRows + 23) / 24;  // 24 rows/round

    // ---- staging: f32 emb rows -> bf16 LDS, swizzled ----
    // thread t: row slot rs = t>>3 (24 rows/round), 32B f32 piece ch8 = t&7.
    // 24 % 8 == 0 -> p&7 == rs&7 (per-lane constant swizzle, read-side match).
    const int rs = tid >> 3;
    const int ch8 = tid & 7;
    const u32 swz = (u32)((ch8 ^ (rs & 7)) << 4);

    // all ids BEFORE any gather (R16 lesson); masked rows -> zero row (R18)
    int ids[RND9];
#pragma unroll
    for (int j = 0; j < RND9; ++j) {
        ids[j] = 0;
        if (j < rounds) {
            int p = j * 24 + rs;
            int q = (p < L_SEQ) ? p : (L_SEQ - 1);
            int idv = xrow[q];
            idv = max(0, min(idv, Vn - 1));
            ids[j] = (p < len) ? idv : 0;
        }
    }

    {
        // 3 slots, consume at j-2 (2 rounds in flight). slot(j) = j%3 and
        // slot(j-2) = (j+1)%3 DIFFER -- the R20 bug was consume at j-3 which
        // aliased the slot loaded in the same iteration.
        float4 fq[3][2];
#pragma unroll
        for (int j = 0; j < RND9 + 2; ++j) {
            if (j < RND9 && j < rounds) {
                const float* rp = emb + (size_t)ids[j] * 64 + ch8 * 8;
                fq[j % 3][0] = *(const float4*)(rp);
                fq[j % 3][1] = *(const float4*)(rp + 4);
            }
            int k = j - 2;
            if (k >= 0 && k < rounds) {
                int p = k * 24 + rs;
                if (p < stRows) {  // last round partial: lane-divergent guard ok
                    u32x4 wv_;
                    wv_.x = pk2bf(fq[k % 3][0].x, fq[k % 3][0].y);
                    wv_.y = pk2bf(fq[k % 3][0].z, fq[k % 3][0].w);
                    wv_.z = pk2bf(fq[k % 3][1].x, fq[k % 3][1].y);
                    wv_.w = pk2bf(fq[k % 3][1].z, fq[k % 3][1].w);
                    u32 off = (u32)p * 128 + swz;
                    *(bf16x8*)(ldsb + off) = __builtin_bit_cast(bf16x8, wv_);
                }
            }
        }
    }
    __syncthreads();

    // ---- tile loop: A-frags from LDS. swizzle term (col&7)<<4 is per-lane
    // constant (rows advance by 16 -> p&7 == col&7). r1 addr = r0 addr ^ 64.
    const u32 c0 = (u32)((g * 16) ^ ((col & 7) << 4));
    u32 ra = (u32)col * 128 + c0;

    float NUM[4] = {0.f, 0.f, 0.f, 0.f};
    float DEN = 0.f;

    bf16x8 a0 = *(const bf16x8*)(ldsb + ra);
    bf16x8 a1 = *(const bf16x8*)(ldsb + (ra ^ 64u));

    for (int t = 0; t < nt; ++t) {
        bf16x8 n0 = a0, n1 = a1;
        if (t + 1 < nt) {
            u32 rn = ra + 2048u;
            n0 = *(const bf16x8*)(ldsb + rn);
            n1 = *(const bf16x8*)(ldsb + (rn ^ 64u));
        }
        ra += 2048u;

        f32x4 E[4];
#pragma unroll
        for (int c = 0; c < 4; ++c) {
            f32x4 cc = {TB[c], TB[c], TB[c], TB[c]};
            cc = __builtin_amdgcn_mfma_f32_16x16x32_bf16(a0, Bf[c][0], cc, 0, 0, 0);
            cc = __builtin_amdgcn_mfma_f32_16x16x32_bf16(a1, Bf[c][1], cc, 0, 0, 0);
            E[c].x = fmaxf(cc.x, 0.f);
            E[c].y = fmaxf(cc.y, 0.f);
            E[c].z = fmaxf(cc.z, 0.f);
            E[c].w = fmaxf(cc.w, 0.f);
        }
        float p0 = E[0].x * AW[0] + E[1].x * AW[1] + E[2].x * AW[2] + E[3].x * AW[3];
        float p1 = E[0].y * AW[0] + E[1].y * AW[1] + E[2].y * AW[2] + E[3].y * AW[3];
        float p2 = E[0].z * AW[0] + E[1].z * AW[1] + E[2].z * AW[2] + E[3].z * AW[3];
        float p3 = E[0].w * AW[0] + E[1].w * AW[1] + E[2].w * AW[2] + E[3].w * AW[3];
        p0 = row16_sum(p0);
        p1 = row16_sum(p1);
        p2 = row16_sum(p2);
        p3 = row16_sum(p3);

        float s0 = exp2f(fmaxf(p0 + AB, 0.f));
        float s1 = exp2f(fmaxf(p1 + AB, 0.f));
        float s2 = exp2f(fmaxf(p2 + AB, 0.f));
        float s3 = exp2f(fmaxf(p3 + AB, 0.f));
        if (t == nt - 1) {  // wave-uniform: only the last (partial) tile masks
            int lrow = (t << 4) + 4 * g;
            s0 = (lrow + 0 < len) ? s0 : 0.f;
            s1 = (lrow + 1 < len) ? s1 : 0.f;
            s2 = (lrow + 2 < len) ? s2 : 0.f;
            s3 = (lrow + 3 < len) ? s3 : 0.f;
        }
        DEN += s0 + s1 + s2 + s3;
#pragma unroll
        for (int c = 0; c < 4; ++c)
            NUM[c] += s0 * E[c].x + s1 * E[c].y + s2 * E[c].z + s3 * E[c].w;

        a0 = n0;
        a1 = n1;
    }

    // fold row-groups -> wave totals; write this attr's rep
    {
        float d = DEN;
        d += __shfl_xor(d, 16, 64);
        d += __shfl_xor(d, 32, 64);
        float rden = 1.0f / fmaxf(d, 1e-20f);  // den >= 1 when len >= 1
#pragma unroll
        for (int c = 0; c < 4; ++c) {
            float v = NUM[c];
            v += __shfl_xor(v, 16, 64);
            v += __shfl_xor(v, 32, 64);
            if (g == 0) rep[a][c * 16 + col] = tanhf(v * rden);
        }
    }
    __syncthreads();

    // epilogue balanced: wave a -> outputs {a, a+3, ..., a+15} (6 each).
    // torch interleave u[3d+aa]=rep[aa][d]; seg s covers u[64s:64s+64] @ Ws
#pragma unroll
    for (int r = 0; r < 6; ++r) {
        int o = a + 3 * r;
        int seg = (o < 2) ? 0 : ((o < 8) ? 1 : 2);
        int k = o - ((seg == 0) ? 0 : ((seg == 1) ? 2 : 8));
        int AL = (seg == 0) ? 2 : ((seg == 1) ? 6 : 10);
        const float* Wp = (seg == 0) ? W0 : ((seg == 1) ? W1 : W2);
        int gg = seg * 64 + lane;
        float v = rep[gg % 3][gg / 3];
        float pz = wave_sumf(v * Wp[lane * AL + k]);
        if (lane == 0) out[b * 18 + o] = pz * ob[b * 18 + o];
    }
}

extern "C" void kernel_launch(void* const* d_in, const int* in_sizes, int n_in,
                              void* d_out, int out_size, void* d_ws, size_t ws_size,
                              hipStream_t stream) {
    const int* x = (const int*)d_in[0];
    const void* xmask = d_in[1];
    // d_in[2] = y : unused
    const float* ob = (const float*)d_in[3];
    const float* emb = (const float*)d_in[4];
    const float* tranW = (const float*)d_in[5];
    const float* tranb = (const float*)d_in[6];
    const float* attW = (const float*)d_in[7];
    const float* attb = (const float*)d_in[8];
    const float* W0 = (const float*)d_in[9];
    const float* W1 = (const float*)d_in[10];
    const float* W2 = (const float*)d_in[11];

    const int Bn = in_sizes[0] / L_SEQ;  // 4096
    const int Vn = in_sizes[4] / 64;     // vocab rows

    // single fused launch: no workspace, no prep kernel, no inter-kernel drain
    etna_fused<<<Bn, 192, 0, stream>>>(x, xmask, ob, emb, tranW, tranb, attW,
                                       attb, W0, W1, W2, (float*)d_out, Vn);
}